// Round 9
// baseline (1723.996 us; speedup 1.0000x reference)
//
#include <hip/hip_runtime.h>
#include <stdint.h>

#define N_NODES 100000
#define CH 128
#define K_NEIGH 16
#define XS_STRIDE 68   // 64 + 4 pad: float4 rows, conflict-light

// Fused kernel (audited rounds 4/5/8, pure f32 VALU, f32 OUTPUT):
//   Out[o][n] = sum_c W1[o][c]*X[c][n]
//             + sum_c W2[o][c]*mean_k X[c][adj[n][k]]
//             + B1[o] + B2[o]
// X [C][N], W [o][c], adj [N][K], Out [O][N]. 64-node tile, 256 threads.
__global__ __launch_bounds__(256, 2) void k_fused(
    const float* __restrict__ X,    // [C][N] f32
    const int*   __restrict__ adj,  // [N][K] int32
    const float* __restrict__ W1,   // [o][c] f32
    const float* __restrict__ B1,
    const float* __restrict__ W2,
    const float* __restrict__ B2,
    float*       __restrict__ Out)  // [O][N] f32  <-- THE FIX
{
    __shared__ __align__(16) float Xs[CH * XS_STRIDE];  // X tile   [c][n]
    __shared__ __align__(16) float As[CH * XS_STRIDE];  // agg tile [c][n]
    __shared__ int adjS[64 * K_NEIGH];

    const int t  = threadIdx.x;
    const int n0 = blockIdx.x * 64;
    const int V  = (N_NODES - n0 < 64) ? (N_NODES - n0) : 64;

    // ---- stage adj rows for this tile (guarded) ----
    {
        const int base  = n0 * K_NEIGH;
        const int valid = V * K_NEIGH;
        for (int idx = t; idx < 64 * K_NEIGH; idx += 256)
            adjS[idx] = (idx < valid) ? adj[base + idx] : 0;
    }

    // ---- stage X tile (f32, guarded) ----
    for (int it = 0; it < 32; ++it) {
        const int idx = t + it * 256;
        const int n = idx & 63, c = idx >> 6;
        Xs[c * XS_STRIDE + n] =
            (n < V) ? X[(size_t)c * N_NODES + n0 + n] : 0.0f;
    }
    __syncthreads();

    // ---- gather agg tile: thread -> node (t&63), channel quarter (t>>6) ----
    {
        const int n_l = t & 63, q = t >> 6;
        int js[K_NEIGH];
#pragma unroll
        for (int k = 0; k < K_NEIGH; ++k) js[k] = adjS[n_l * K_NEIGH + k];
        if (n_l < V) {
            for (int cc = 0; cc < 32; ++cc) {
                const int c = q * 32 + cc;
                const float* xc = X + (size_t)c * N_NODES;
                float s = 0.0f;
#pragma unroll
                for (int k = 0; k < K_NEIGH; ++k) s += xc[js[k]];
                As[c * XS_STRIDE + n_l] = s * 0.0625f;
            }
        } else {
            for (int cc = 0; cc < 32; ++cc)
                As[(q * 32 + cc) * XS_STRIDE + n_l] = 0.0f;
        }
    }
    __syncthreads();

    // ---- dual GEMM: thread owns o = (t>>3)*4+i (i<4), n = (t&7)*8+j (j<8) ----
    const int ng = t & 7, og = t >> 3;
    float acc[4][8];
#pragma unroll
    for (int i = 0; i < 4; ++i)
#pragma unroll
        for (int j = 0; j < 8; ++j) acc[i][j] = 0.0f;

    const float* w1p = W1 + (og * 4) * CH;
    const float* w2p = W2 + (og * 4) * CH;
    for (int c = 0; c < CH; ++c) {
        float xv[8], av[8], w1v[4], w2v[4];
        *(float4*)&xv[0] = *(const float4*)&Xs[c * XS_STRIDE + ng * 8];
        *(float4*)&xv[4] = *(const float4*)&Xs[c * XS_STRIDE + ng * 8 + 4];
        *(float4*)&av[0] = *(const float4*)&As[c * XS_STRIDE + ng * 8];
        *(float4*)&av[4] = *(const float4*)&As[c * XS_STRIDE + ng * 8 + 4];
#pragma unroll
        for (int i = 0; i < 4; ++i) {
            w1v[i] = w1p[i * CH + c];
            w2v[i] = w2p[i * CH + c];
        }
#pragma unroll
        for (int i = 0; i < 4; ++i)
#pragma unroll
            for (int j = 0; j < 8; ++j)
                acc[i][j] += w1v[i] * xv[j] + w2v[i] * av[j];
    }

    // ---- pivot through LDS (reuse Xs), store Out o-major coalesced, f32 ----
    __syncthreads();
    float* Zt = Xs;   // [128 o][stride 68]
#pragma unroll
    for (int i = 0; i < 4; ++i) {
        *(float4*)&Zt[(og * 4 + i) * XS_STRIDE + ng * 8]     = *(float4*)&acc[i][0];
        *(float4*)&Zt[(og * 4 + i) * XS_STRIDE + ng * 8 + 4] = *(float4*)&acc[i][4];
    }
    __syncthreads();
    for (int it = 0; it < 32; ++it) {
        const int idx = t + it * 256;
        const int n = idx & 63, o = idx >> 6;
        if (n < V) {
            Out[(size_t)o * N_NODES + n0 + n] =
                Zt[o * XS_STRIDE + n] + B1[o] + B2[o];
        }
    }
}

extern "C" void kernel_launch(void* const* d_in, const int* in_sizes, int n_in,
                              void* d_out, int out_size, void* d_ws, size_t ws_size,
                              hipStream_t stream) {
    const float* X   = (const float*)d_in[0];
    const int*   adj = (const int*)d_in[1];
    const float* W1  = (const float*)d_in[2];
    const float* B1  = (const float*)d_in[3];
    const float* W2  = (const float*)d_in[4];
    const float* B2  = (const float*)d_in[5];
    float* Out = (float*)d_out;

    const int nblocks = (N_NODES + 63) / 64;  // 1563
    k_fused<<<nblocks, 256, 0, stream>>>(X, adj, W1, B1, W2, B2, Out);
}